// Round 1
// baseline (2296.494 us; speedup 1.0000x reference)
//
#include <hip/hip_runtime.h>

#define NN 100000
#define NE 2500000

__device__ __forceinline__ float relu_(float x){ return fmaxf(x, 0.f); }

// h[n, 0:32] = relu(nf[n,0:2] @ W_in + b_in)
__global__ __launch_bounds__(256) void k_node_embed(
    const float* __restrict__ nf, const float* __restrict__ Win,
    const float* __restrict__ bin, float* __restrict__ h)
{
  int n = blockIdx.x * 256 + threadIdx.x;
  if (n >= NN) return;
  float f0 = nf[2*n], f1 = nf[2*n+1];
  const float4* W0 = (const float4*)Win;        // W_in[0][:]
  const float4* W1 = (const float4*)(Win + 32); // W_in[1][:]
  const float4* B  = (const float4*)bin;
  float4* h4 = (float4*)(h + (size_t)n * 32);
#pragma unroll
  for (int j = 0; j < 8; ++j) {
    float4 w0 = W0[j], w1 = W1[j], b = B[j], r;
    r.x = relu_(fmaf(f0, w0.x, fmaf(f1, w1.x, b.x)));
    r.y = relu_(fmaf(f0, w0.y, fmaf(f1, w1.y, b.y)));
    r.z = relu_(fmaf(f0, w0.z, fmaf(f1, w1.z, b.z)));
    r.w = relu_(fmaf(f0, w0.w, fmaf(f1, w1.w, b.w)));
    h4[j] = r;
  }
}

__global__ __launch_bounds__(256) void k_deg(const int* __restrict__ row,
                                             float* __restrict__ deg)
{
  int e = blockIdx.x * 256 + threadIdx.x;
  if (e >= NE) return;
  unsafeAtomicAdd(&deg[row[e]], 1.0f);
}

// agg[row[e], :] += h[col[e], :]   (8 threads/edge, float4 each)
__global__ __launch_bounds__(256) void k_scatter(
    const int* __restrict__ row, const int* __restrict__ col,
    const float* __restrict__ h, float* __restrict__ agg)
{
  int gid = blockIdx.x * 256 + threadIdx.x;
  int e = gid >> 3, q = gid & 7;
  if (e >= NE) return;
  int r = row[e], c = col[e];
  float4 val = ((const float4*)h)[c * 8 + q];
  float* dst = agg + (size_t)r * 32 + q * 4;
  unsafeAtomicAdd(dst + 0, val.x);
  unsafeAtomicAdd(dst + 1, val.y);
  unsafeAtomicAdd(dst + 2, val.z);
  unsafeAtomicAdd(dst + 3, val.w);
}

// h[n,:] = relu(concat(h[n,:], agg[n,:]/deg[n]) @ W[64,32] + b)   (in place)
__global__ __launch_bounds__(256) void k_update(
    float* __restrict__ h, const float* __restrict__ agg,
    const float* __restrict__ deg, const float* __restrict__ W,
    const float* __restrict__ b)
{
  __shared__ float Ws[64 * 32];
  __shared__ float bs[32];
  int t = threadIdx.x;
  for (int i = t; i < 2048; i += 256) Ws[i] = W[i];
  if (t < 32) bs[t] = b[t];
  __syncthreads();
  int n = blockIdx.x * 256 + t;
  if (n >= NN) return;

  float x[64];
  const float4* h4 = (const float4*)(h + (size_t)n * 32);
  const float4* a4 = (const float4*)(agg + (size_t)n * 32);
  float dinv = 1.0f / fmaxf(deg[n], 1.0f);
#pragma unroll
  for (int j = 0; j < 8; ++j) {
    float4 tv = h4[j];
    x[4*j+0] = tv.x; x[4*j+1] = tv.y; x[4*j+2] = tv.z; x[4*j+3] = tv.w;
  }
#pragma unroll
  for (int j = 0; j < 8; ++j) {
    float4 tv = a4[j];
    x[32+4*j+0] = tv.x * dinv; x[32+4*j+1] = tv.y * dinv;
    x[32+4*j+2] = tv.z * dinv; x[32+4*j+3] = tv.w * dinv;
  }
  float acc[32];
#pragma unroll
  for (int j = 0; j < 32; ++j) acc[j] = bs[j];
  for (int k = 0; k < 64; ++k) {
    float xk = x[k];
    const float* wr = Ws + k * 32;
#pragma unroll
    for (int j = 0; j < 32; ++j) acc[j] = fmaf(xk, wr[j], acc[j]);
  }
  float4* o4 = (float4*)(h + (size_t)n * 32);
#pragma unroll
  for (int j = 0; j < 8; ++j) {
    float4 r;
    r.x = relu_(acc[4*j+0]); r.y = relu_(acc[4*j+1]);
    r.z = relu_(acc[4*j+2]); r.w = relu_(acc[4*j+3]);
    o4[j] = r;
  }
}

// u[n,:] = h[n,:] @ We1[0:32,:] + be1 ;  v[n,:] = h[n,:] @ We1[32:64,:]
__global__ __launch_bounds__(256) void k_uv(
    const float* __restrict__ h, const float* __restrict__ We1,
    const float* __restrict__ be1, float* __restrict__ u, float* __restrict__ v)
{
  __shared__ float Ws[64 * 32];
  __shared__ float bs[32];
  int t = threadIdx.x;
  for (int i = t; i < 2048; i += 256) Ws[i] = We1[i];
  if (t < 32) bs[t] = be1[t];
  __syncthreads();
  int n = blockIdx.x * 256 + t;
  if (n >= NN) return;

  float x[32];
  const float4* h4 = (const float4*)(h + (size_t)n * 32);
#pragma unroll
  for (int j = 0; j < 8; ++j) {
    float4 tv = h4[j];
    x[4*j+0] = tv.x; x[4*j+1] = tv.y; x[4*j+2] = tv.z; x[4*j+3] = tv.w;
  }
  float au[32], av[32];
#pragma unroll
  for (int j = 0; j < 32; ++j) { au[j] = bs[j]; av[j] = 0.f; }
  for (int k = 0; k < 32; ++k) {
    float xk = x[k];
    const float* wu = Ws + k * 32;
    const float* wv = Ws + (32 + k) * 32;
#pragma unroll
    for (int j = 0; j < 32; ++j) {
      au[j] = fmaf(xk, wu[j], au[j]);
      av[j] = fmaf(xk, wv[j], av[j]);
    }
  }
  float4* u4 = (float4*)(u + (size_t)n * 32);
  float4* v4 = (float4*)(v + (size_t)n * 32);
#pragma unroll
  for (int j = 0; j < 8; ++j) {
    float4 ru, rv;
    ru.x = au[4*j+0]; ru.y = au[4*j+1]; ru.z = au[4*j+2]; ru.w = au[4*j+3];
    rv.x = av[4*j+0]; rv.y = av[4*j+1]; rv.z = av[4*j+2]; rv.w = av[4*j+3];
    u4[j] = ru; v4[j] = rv;
  }
}

// flux[e] = relu(u[row[e],:] + v[col[e],:]) . We2 + be2    (8 threads/edge)
__global__ __launch_bounds__(256) void k_flux(
    const int* __restrict__ row, const int* __restrict__ col,
    const float* __restrict__ u, const float* __restrict__ v,
    const float* __restrict__ We2, const float* __restrict__ be2,
    float* __restrict__ out)
{
  int gid = blockIdx.x * 256 + threadIdx.x;
  int e = gid >> 3, q = gid & 7;
  if (e >= NE) return;
  int r = row[e], c = col[e];
  float4 a = ((const float4*)u)[r * 8 + q];
  float4 b = ((const float4*)v)[c * 8 + q];
  float4 w = ((const float4*)We2)[q];
  float p = relu_(a.x + b.x) * w.x
          + relu_(a.y + b.y) * w.y
          + relu_(a.z + b.z) * w.z
          + relu_(a.w + b.w) * w.w;
  p += __shfl_xor(p, 1, 8);
  p += __shfl_xor(p, 2, 8);
  p += __shfl_xor(p, 4, 8);
  if (q == 0) out[e] = p + be2[0];
}

extern "C" void kernel_launch(void* const* d_in, const int* in_sizes, int n_in,
                              void* d_out, int out_size, void* d_ws, size_t ws_size,
                              hipStream_t stream) {
  const float* nf   = (const float*)d_in[0];
  const int*   ei   = (const int*)d_in[1];   // [2, E] int32: row then col
  const float* Win  = (const float*)d_in[2];
  const float* bin  = (const float*)d_in[3];
  const float* Wupd = (const float*)d_in[4]; // [2, 64, 32]
  const float* bupd = (const float*)d_in[5]; // [2, 32]
  const float* We1  = (const float*)d_in[6]; // [64, 32]
  const float* be1  = (const float*)d_in[7];
  const float* We2  = (const float*)d_in[8]; // [32]
  const float* be2  = (const float*)d_in[9];
  float* out = (float*)d_out;

  const int* row = ei;
  const int* col = ei + NE;

  char* ws = (char*)d_ws;
  const size_t HB = (size_t)NN * 32 * 4;        // 12.8 MB
  float* h   = (float*)(ws);
  float* agg = (float*)(ws + HB);               // reused as u later
  float* v   = (float*)(ws + 2 * HB);
  float* deg = (float*)(ws + 3 * HB);

  hipMemsetAsync(deg, 0, (size_t)NN * 4, stream);
  k_node_embed<<<(NN + 255) / 256, 256, 0, stream>>>(nf, Win, bin, h);
  k_deg<<<(NE + 255) / 256, 256, 0, stream>>>(row, deg);

  for (int l = 0; l < 2; ++l) {
    hipMemsetAsync(agg, 0, HB, stream);
    k_scatter<<<(NE * 8) / 256, 256, 0, stream>>>(row, col, h, agg);
    k_update<<<(NN + 255) / 256, 256, 0, stream>>>(h, agg, deg,
                                                   Wupd + l * 2048, bupd + l * 32);
  }

  k_uv<<<(NN + 255) / 256, 256, 0, stream>>>(h, We1, be1, agg, v);
  k_flux<<<(NE * 8) / 256, 256, 0, stream>>>(row, col, agg, v, We2, be2, out);
}

// Round 2
// 575.604 us; speedup vs baseline: 3.9897x; 3.9897x over previous
//
#include <hip/hip_runtime.h>

#define NN 100000
#define NE 2500000

__device__ __forceinline__ float relu_(float x){ return fmaxf(x, 0.f); }

// h[n, 0:32] = relu(nf[n,0:2] @ W_in + b_in)
__global__ __launch_bounds__(256) void k_node_embed(
    const float* __restrict__ nf, const float* __restrict__ Win,
    const float* __restrict__ bin, float* __restrict__ h)
{
  int n = blockIdx.x * 256 + threadIdx.x;
  if (n >= NN) return;
  float f0 = nf[2*n], f1 = nf[2*n+1];
  const float4* W0 = (const float4*)Win;
  const float4* W1 = (const float4*)(Win + 32);
  const float4* B  = (const float4*)bin;
  float4* h4 = (float4*)(h + (size_t)n * 32);
#pragma unroll
  for (int j = 0; j < 8; ++j) {
    float4 w0 = W0[j], w1 = W1[j], b = B[j], r;
    r.x = relu_(fmaf(f0, w0.x, fmaf(f1, w1.x, b.x)));
    r.y = relu_(fmaf(f0, w0.y, fmaf(f1, w1.y, b.y)));
    r.z = relu_(fmaf(f0, w0.z, fmaf(f1, w1.z, b.z)));
    r.w = relu_(fmaf(f0, w0.w, fmaf(f1, w1.w, b.w)));
    h4[j] = r;
  }
}

// ---- CSR build: counting sort of edges by row ----

__global__ __launch_bounds__(256) void k_count(const int* __restrict__ row,
                                               int* __restrict__ cnt)
{
  int e = blockIdx.x * 256 + threadIdx.x;
  if (e >= NE) return;
  atomicAdd(&cnt[row[e]], 1);
}

__global__ __launch_bounds__(256) void k_bsum(const int* __restrict__ cnt,
                                              int* __restrict__ bsum)
{
  __shared__ int s[256];
  int t = threadIdx.x;
  int n = blockIdx.x * 256 + t;
  s[t] = (n < NN) ? cnt[n] : 0;
  __syncthreads();
  for (int off = 128; off > 0; off >>= 1) {
    if (t < off) s[t] += s[t + off];
    __syncthreads();
  }
  if (t == 0) bsum[blockIdx.x] = s[0];
}

// single block of 512: exclusive scan of nb (<512) block sums
__global__ __launch_bounds__(512) void k_bscan(const int* __restrict__ bsum,
                                               int* __restrict__ bpre, int nb)
{
  __shared__ int s[512];
  int t = threadIdx.x;
  int my = (t < nb) ? bsum[t] : 0;
  s[t] = my;
  __syncthreads();
  for (int off = 1; off < 512; off <<= 1) {
    int v = (t >= off) ? s[t - off] : 0;
    __syncthreads();
    s[t] += v;
    __syncthreads();
  }
  if (t < nb) bpre[t] = s[t] - my;   // exclusive
}

__global__ __launch_bounds__(256) void k_scan_apply(
    const int* __restrict__ cnt, const int* __restrict__ bpre,
    int* __restrict__ rowptr, int* __restrict__ cursor)
{
  __shared__ int s[256];
  int t = threadIdx.x, b = blockIdx.x;
  int n = b * 256 + t;
  int my = (n < NN) ? cnt[n] : 0;
  s[t] = my;
  __syncthreads();
  for (int off = 1; off < 256; off <<= 1) {
    int v = (t >= off) ? s[t - off] : 0;
    __syncthreads();
    s[t] += v;
    __syncthreads();
  }
  if (n < NN) {
    int ex = bpre[b] + s[t] - my;    // exclusive global prefix
    rowptr[n] = ex;
    cursor[n] = ex;
  }
  if (n == 0) rowptr[NN] = NE;
}

__global__ __launch_bounds__(256) void k_place(
    const int* __restrict__ row, const int* __restrict__ col,
    int* __restrict__ cursor, int* __restrict__ ecol)
{
  int e = blockIdx.x * 256 + threadIdx.x;
  if (e >= NE) return;
  int r = row[e];
  int p = atomicAdd(&cursor[r], 1);
  ecol[p] = col[e];
}

// ---- aggregation as gather: agg[n,:] = sum_{i in seg(n)} h[ecol[i],:] / max(deg,1) ----
__global__ __launch_bounds__(256) void k_aggregate(
    const int* __restrict__ rowptr, const int* __restrict__ ecol,
    const float* __restrict__ h, float* __restrict__ agg)
{
  int gid = blockIdx.x * 256 + threadIdx.x;
  int n = gid >> 3, q = gid & 7;
  if (n >= NN) return;
  int s = rowptr[n], e = rowptr[n + 1];
  const float4* h4 = (const float4*)h;
  float4 acc = {0.f, 0.f, 0.f, 0.f};
  for (int i = s; i < e; ++i) {
    int c = ecol[i];
    float4 x = h4[c * 8 + q];
    acc.x += x.x; acc.y += x.y; acc.z += x.z; acc.w += x.w;
  }
  float dinv = 1.0f / fmaxf((float)(e - s), 1.0f);
  acc.x *= dinv; acc.y *= dinv; acc.z *= dinv; acc.w *= dinv;
  ((float4*)agg)[n * 8 + q] = acc;
}

// h[n,:] = relu(concat(h[n,:], agg[n,:]) @ W[64,32] + b)   (agg pre-normalized)
__global__ __launch_bounds__(256) void k_update(
    float* __restrict__ h, const float* __restrict__ agg,
    const float* __restrict__ W, const float* __restrict__ b)
{
  __shared__ float Ws[64 * 32];
  __shared__ float bs[32];
  int t = threadIdx.x;
  for (int i = t; i < 2048; i += 256) Ws[i] = W[i];
  if (t < 32) bs[t] = b[t];
  __syncthreads();
  int n = blockIdx.x * 256 + t;
  if (n >= NN) return;

  float x[64];
  const float4* h4 = (const float4*)(h + (size_t)n * 32);
  const float4* a4 = (const float4*)(agg + (size_t)n * 32);
#pragma unroll
  for (int j = 0; j < 8; ++j) {
    float4 tv = h4[j];
    x[4*j+0] = tv.x; x[4*j+1] = tv.y; x[4*j+2] = tv.z; x[4*j+3] = tv.w;
  }
#pragma unroll
  for (int j = 0; j < 8; ++j) {
    float4 tv = a4[j];
    x[32+4*j+0] = tv.x; x[32+4*j+1] = tv.y;
    x[32+4*j+2] = tv.z; x[32+4*j+3] = tv.w;
  }
  float acc[32];
#pragma unroll
  for (int j = 0; j < 32; ++j) acc[j] = bs[j];
  for (int k = 0; k < 64; ++k) {
    float xk = x[k];
    const float* wr = Ws + k * 32;
#pragma unroll
    for (int j = 0; j < 32; ++j) acc[j] = fmaf(xk, wr[j], acc[j]);
  }
  float4* o4 = (float4*)(h + (size_t)n * 32);
#pragma unroll
  for (int j = 0; j < 8; ++j) {
    float4 r;
    r.x = relu_(acc[4*j+0]); r.y = relu_(acc[4*j+1]);
    r.z = relu_(acc[4*j+2]); r.w = relu_(acc[4*j+3]);
    o4[j] = r;
  }
}

// u[n,:] = h[n,:] @ We1[0:32,:] + be1 ;  v[n,:] = h[n,:] @ We1[32:64,:]
__global__ __launch_bounds__(256) void k_uv(
    const float* __restrict__ h, const float* __restrict__ We1,
    const float* __restrict__ be1, float* __restrict__ u, float* __restrict__ v)
{
  __shared__ float Ws[64 * 32];
  __shared__ float bs[32];
  int t = threadIdx.x;
  for (int i = t; i < 2048; i += 256) Ws[i] = We1[i];
  if (t < 32) bs[t] = be1[t];
  __syncthreads();
  int n = blockIdx.x * 256 + t;
  if (n >= NN) return;

  float x[32];
  const float4* h4 = (const float4*)(h + (size_t)n * 32);
#pragma unroll
  for (int j = 0; j < 8; ++j) {
    float4 tv = h4[j];
    x[4*j+0] = tv.x; x[4*j+1] = tv.y; x[4*j+2] = tv.z; x[4*j+3] = tv.w;
  }
  float au[32], av[32];
#pragma unroll
  for (int j = 0; j < 32; ++j) { au[j] = bs[j]; av[j] = 0.f; }
  for (int k = 0; k < 32; ++k) {
    float xk = x[k];
    const float* wu = Ws + k * 32;
    const float* wv = Ws + (32 + k) * 32;
#pragma unroll
    for (int j = 0; j < 32; ++j) {
      au[j] = fmaf(xk, wu[j], au[j]);
      av[j] = fmaf(xk, wv[j], av[j]);
    }
  }
  float4* u4 = (float4*)(u + (size_t)n * 32);
  float4* v4 = (float4*)(v + (size_t)n * 32);
#pragma unroll
  for (int j = 0; j < 8; ++j) {
    float4 ru, rv;
    ru.x = au[4*j+0]; ru.y = au[4*j+1]; ru.z = au[4*j+2]; ru.w = au[4*j+3];
    rv.x = av[4*j+0]; rv.y = av[4*j+1]; rv.z = av[4*j+2]; rv.w = av[4*j+3];
    u4[j] = ru; v4[j] = rv;
  }
}

// flux[e] = relu(u[row[e],:] + v[col[e],:]) . We2 + be2    (8 threads/edge)
__global__ __launch_bounds__(256) void k_flux(
    const int* __restrict__ row, const int* __restrict__ col,
    const float* __restrict__ u, const float* __restrict__ v,
    const float* __restrict__ We2, const float* __restrict__ be2,
    float* __restrict__ out)
{
  int gid = blockIdx.x * 256 + threadIdx.x;
  int e = gid >> 3, q = gid & 7;
  if (e >= NE) return;
  int r = row[e], c = col[e];
  float4 a = ((const float4*)u)[r * 8 + q];
  float4 b = ((const float4*)v)[c * 8 + q];
  float4 w = ((const float4*)We2)[q];
  float p = relu_(a.x + b.x) * w.x
          + relu_(a.y + b.y) * w.y
          + relu_(a.z + b.z) * w.z
          + relu_(a.w + b.w) * w.w;
  p += __shfl_xor(p, 1, 8);
  p += __shfl_xor(p, 2, 8);
  p += __shfl_xor(p, 4, 8);
  if (q == 0) out[e] = p + be2[0];
}

extern "C" void kernel_launch(void* const* d_in, const int* in_sizes, int n_in,
                              void* d_out, int out_size, void* d_ws, size_t ws_size,
                              hipStream_t stream) {
  const float* nf   = (const float*)d_in[0];
  const int*   ei   = (const int*)d_in[1];   // [2, E] int32: row then col
  const float* Win  = (const float*)d_in[2];
  const float* bin  = (const float*)d_in[3];
  const float* Wupd = (const float*)d_in[4]; // [2, 64, 32]
  const float* bupd = (const float*)d_in[5]; // [2, 32]
  const float* We1  = (const float*)d_in[6]; // [64, 32]
  const float* be1  = (const float*)d_in[7];
  const float* We2  = (const float*)d_in[8]; // [32]
  const float* be2  = (const float*)d_in[9];
  float* out = (float*)d_out;

  const int* row = ei;
  const int* col = ei + NE;

  char* ws = (char*)d_ws;
  const size_t HB = (size_t)NN * 32 * 4;        // 12.8 MB
  float* h    = (float*)(ws);
  float* agg  = (float*)(ws + HB);              // reused as u later
  float* v    = (float*)(ws + 2 * HB);          // ecol (10MB) aliases here first
  int*   ecol = (int*)(ws + 2 * HB);            // dead before v is written
  int*   rowptr = (int*)(ws + 3 * HB);          // NN+1 ints
  int*   cnt    = (int*)(ws + 3 * HB + 400016); // NN ints (also cursor)
  int*   bsum   = (int*)(ws + 3 * HB + 800016); // 512 ints
  int*   bpre   = (int*)(ws + 3 * HB + 802064); // 512 ints

  const int NB = (NN + 255) / 256;  // 391 blocks < 512

  hipMemsetAsync(cnt, 0, (size_t)NN * 4, stream);
  k_node_embed<<<NB, 256, 0, stream>>>(nf, Win, bin, h);
  k_count<<<(NE + 255) / 256, 256, 0, stream>>>(row, cnt);
  k_bsum<<<NB, 256, 0, stream>>>(cnt, bsum);
  k_bscan<<<1, 512, 0, stream>>>(bsum, bpre, NB);
  k_scan_apply<<<NB, 256, 0, stream>>>(cnt, bpre, rowptr, /*cursor=*/cnt);
  k_place<<<(NE + 255) / 256, 256, 0, stream>>>(row, col, /*cursor=*/cnt, ecol);

  for (int l = 0; l < 2; ++l) {
    k_aggregate<<<(NN * 8 + 255) / 256, 256, 0, stream>>>(rowptr, ecol, h, agg);
    k_update<<<NB, 256, 0, stream>>>(h, agg, Wupd + l * 2048, bupd + l * 32);
  }

  k_uv<<<NB, 256, 0, stream>>>(h, We1, be1, agg, v);
  k_flux<<<(NE * 8 + 255) / 256, 256, 0, stream>>>(row, col, agg, v, We2, be2, out);
}

// Round 3
// 318.408 us; speedup vs baseline: 7.2124x; 1.8078x over previous
//
#include <hip/hip_runtime.h>

#define NN 100000
#define NE 2500000
#define RANGE 256
#define NBUCK 391                       // ceil(NN/RANGE)
#define CHUNK 8192
#define NBLK_A ((NE + CHUNK - 1) / CHUNK)

__device__ __forceinline__ float relu_(float x){ return fmaxf(x, 0.f); }

// h[n, 0:32] = relu(nf[n,0:2] @ W_in + b_in)
__global__ __launch_bounds__(256) void k_node_embed(
    const float* __restrict__ nf, const float* __restrict__ Win,
    const float* __restrict__ bin, float* __restrict__ h)
{
  int n = blockIdx.x * 256 + threadIdx.x;
  if (n >= NN) return;
  float f0 = nf[2*n], f1 = nf[2*n+1];
  const float4* W0 = (const float4*)Win;
  const float4* W1 = (const float4*)(Win + 32);
  const float4* B  = (const float4*)bin;
  float4* h4 = (float4*)(h + (size_t)n * 32);
#pragma unroll
  for (int j = 0; j < 8; ++j) {
    float4 w0 = W0[j], w1 = W1[j], b = B[j], r;
    r.x = relu_(fmaf(f0, w0.x, fmaf(f1, w1.x, b.x)));
    r.y = relu_(fmaf(f0, w0.y, fmaf(f1, w1.y, b.y)));
    r.z = relu_(fmaf(f0, w0.z, fmaf(f1, w1.z, b.z)));
    r.w = relu_(fmaf(f0, w0.w, fmaf(f1, w1.w, b.w)));
    h4[j] = r;
  }
}

// ---- CSR build: two-level LDS-staged counting sort ----

__global__ __launch_bounds__(512) void k_histA(const int* __restrict__ row,
                                               int* __restrict__ btot)
{
  __shared__ int hist[NBUCK];
  int t = threadIdx.x;
  for (int i = t; i < NBUCK; i += 512) hist[i] = 0;
  __syncthreads();
  int e0 = blockIdx.x * CHUNK + t;
#pragma unroll
  for (int k = 0; k < CHUNK / 512; ++k) {
    int e = e0 + k * 512;
    if (e < NE) atomicAdd(&hist[row[e] >> 8], 1);
  }
  __syncthreads();
  for (int i = t; i < NBUCK; i += 512)
    if (hist[i]) atomicAdd(&btot[i], hist[i]);
}

__global__ __launch_bounds__(512) void k_scanA(const int* __restrict__ btot,
                                               int* __restrict__ bbase,
                                               int* __restrict__ cursorA)
{
  __shared__ int s[512];
  int t = threadIdx.x;
  int my = (t < NBUCK) ? btot[t] : 0;
  s[t] = my;
  __syncthreads();
  for (int off = 1; off < 512; off <<= 1) {
    int v = (t >= off) ? s[t - off] : 0;
    __syncthreads();
    s[t] += v;
    __syncthreads();
  }
  if (t < NBUCK) { int ex = s[t] - my; bbase[t] = ex; cursorA[t] = ex; }
  if (t == 0) bbase[NBUCK] = NE;
}

// partition edges into bucket-contiguous packed keys: (col<<8) | (row&255)
__global__ __launch_bounds__(512) void k_partition(
    const int* __restrict__ row, const int* __restrict__ col,
    int* __restrict__ cursorA, unsigned int* __restrict__ keys)
{
  __shared__ int hist[NBUCK];
  __shared__ int base[NBUCK];
  int t = threadIdx.x;
  for (int i = t; i < NBUCK; i += 512) hist[i] = 0;
  __syncthreads();
  int e0 = blockIdx.x * CHUNK + t;
#pragma unroll
  for (int k = 0; k < CHUNK / 512; ++k) {
    int e = e0 + k * 512;
    if (e < NE) atomicAdd(&hist[row[e] >> 8], 1);
  }
  __syncthreads();
  for (int i = t; i < NBUCK; i += 512) {
    int c = hist[i];
    base[i] = c ? atomicAdd(&cursorA[i], c) : 0;
    hist[i] = 0;
  }
  __syncthreads();
#pragma unroll
  for (int k = 0; k < CHUNK / 512; ++k) {
    int e = e0 + k * 512;
    if (e < NE) {
      int r = row[e];
      int b = r >> 8;
      int idx = atomicAdd(&hist[b], 1);
      keys[base[b] + idx] = ((unsigned)col[e] << 8) | (unsigned)(r & 255);
    }
  }
}

// per-bucket: 256-entry histogram + scan -> rowptr; place col into ecol
__global__ __launch_bounds__(512) void k_passB(
    const int* __restrict__ bbase, const unsigned int* __restrict__ keys,
    int* __restrict__ ecol, int* __restrict__ rowptr)
{
  __shared__ int hist[RANGE];
  __shared__ int sc[RANGE];
  int t = threadIdx.x, b = blockIdx.x;
  int s0 = bbase[b], e0 = bbase[b + 1];
  if (t < RANGE) hist[t] = 0;
  __syncthreads();
  for (int i = s0 + t; i < e0; i += 512)
    atomicAdd(&hist[keys[i] & 255u], 1);
  __syncthreads();
  int my = (t < RANGE) ? hist[t] : 0;
  if (t < RANGE) sc[t] = my;
  __syncthreads();
  for (int off = 1; off < RANGE; off <<= 1) {
    int v = 0;
    if (t < RANGE && t >= off) v = sc[t - off];
    __syncthreads();
    if (t < RANGE) sc[t] += v;
    __syncthreads();
  }
  if (t < RANGE) {
    int ex = sc[t] - my;
    int n = b * RANGE + t;
    if (n <= NN) rowptr[n] = s0 + ex;
    hist[t] = ex;                 // becomes the placement cursor
  }
  __syncthreads();
  for (int i = s0 + t; i < e0; i += 512) {
    unsigned key = keys[i];
    int rl = (int)(key & 255u);
    int idx = atomicAdd(&hist[rl], 1);
    ecol[s0 + idx] = (int)(key >> 8);
  }
}

// ---- aggregation as gather: agg[n,:] = mean_{i in seg(n)} h[ecol[i],:] ----
__global__ __launch_bounds__(256) void k_aggregate(
    const int* __restrict__ rowptr, const int* __restrict__ ecol,
    const float* __restrict__ h, float* __restrict__ agg)
{
  int gid = blockIdx.x * 256 + threadIdx.x;
  int n = gid >> 3, q = gid & 7;
  if (n >= NN) return;
  int s = rowptr[n], e = rowptr[n + 1];
  const float4* h4 = (const float4*)h;
  float4 acc = {0.f, 0.f, 0.f, 0.f};
  for (int i = s; i < e; ++i) {
    int c = ecol[i];
    float4 x = h4[c * 8 + q];
    acc.x += x.x; acc.y += x.y; acc.z += x.z; acc.w += x.w;
  }
  float dinv = 1.0f / fmaxf((float)(e - s), 1.0f);
  acc.x *= dinv; acc.y *= dinv; acc.z *= dinv; acc.w *= dinv;
  ((float4*)agg)[n * 8 + q] = acc;
}

// h[n,:] = relu(concat(h[n,:], agg[n,:]) @ W[64,32] + b)   (in place)
__global__ __launch_bounds__(256) void k_update(
    float* __restrict__ h, const float* __restrict__ agg,
    const float* __restrict__ W, const float* __restrict__ b)
{
  __shared__ float Ws[64 * 32];
  __shared__ float bs[32];
  int t = threadIdx.x;
  for (int i = t; i < 2048; i += 256) Ws[i] = W[i];
  if (t < 32) bs[t] = b[t];
  __syncthreads();
  int n = blockIdx.x * 256 + t;
  if (n >= NN) return;

  float x[64];
  const float4* h4 = (const float4*)(h + (size_t)n * 32);
  const float4* a4 = (const float4*)(agg + (size_t)n * 32);
#pragma unroll
  for (int j = 0; j < 8; ++j) {
    float4 tv = h4[j];
    x[4*j+0] = tv.x; x[4*j+1] = tv.y; x[4*j+2] = tv.z; x[4*j+3] = tv.w;
  }
#pragma unroll
  for (int j = 0; j < 8; ++j) {
    float4 tv = a4[j];
    x[32+4*j+0] = tv.x; x[32+4*j+1] = tv.y;
    x[32+4*j+2] = tv.z; x[32+4*j+3] = tv.w;
  }
  float acc[32];
#pragma unroll
  for (int j = 0; j < 32; ++j) acc[j] = bs[j];
  for (int k = 0; k < 64; ++k) {
    float xk = x[k];
    const float* wr = Ws + k * 32;
#pragma unroll
    for (int j = 0; j < 32; ++j) acc[j] = fmaf(xk, wr[j], acc[j]);
  }
  float4* o4 = (float4*)(h + (size_t)n * 32);
#pragma unroll
  for (int j = 0; j < 8; ++j) {
    float4 r;
    r.x = relu_(acc[4*j+0]); r.y = relu_(acc[4*j+1]);
    r.z = relu_(acc[4*j+2]); r.w = relu_(acc[4*j+3]);
    o4[j] = r;
  }
}

// u[n,:] = h[n,:] @ We1[0:32,:] + be1 ;  v[n,:] = h[n,:] @ We1[32:64,:]
__global__ __launch_bounds__(256) void k_uv(
    const float* __restrict__ h, const float* __restrict__ We1,
    const float* __restrict__ be1, float* __restrict__ u, float* __restrict__ v)
{
  __shared__ float Ws[64 * 32];
  __shared__ float bs[32];
  int t = threadIdx.x;
  for (int i = t; i < 2048; i += 256) Ws[i] = We1[i];
  if (t < 32) bs[t] = be1[t];
  __syncthreads();
  int n = blockIdx.x * 256 + t;
  if (n >= NN) return;

  float x[32];
  const float4* h4 = (const float4*)(h + (size_t)n * 32);
#pragma unroll
  for (int j = 0; j < 8; ++j) {
    float4 tv = h4[j];
    x[4*j+0] = tv.x; x[4*j+1] = tv.y; x[4*j+2] = tv.z; x[4*j+3] = tv.w;
  }
  float au[32], av[32];
#pragma unroll
  for (int j = 0; j < 32; ++j) { au[j] = bs[j]; av[j] = 0.f; }
  for (int k = 0; k < 32; ++k) {
    float xk = x[k];
    const float* wu = Ws + k * 32;
    const float* wv = Ws + (32 + k) * 32;
#pragma unroll
    for (int j = 0; j < 32; ++j) {
      au[j] = fmaf(xk, wu[j], au[j]);
      av[j] = fmaf(xk, wv[j], av[j]);
    }
  }
  float4* u4 = (float4*)(u + (size_t)n * 32);
  float4* v4 = (float4*)(v + (size_t)n * 32);
#pragma unroll
  for (int j = 0; j < 8; ++j) {
    float4 ru, rv;
    ru.x = au[4*j+0]; ru.y = au[4*j+1]; ru.z = au[4*j+2]; ru.w = au[4*j+3];
    rv.x = av[4*j+0]; rv.y = av[4*j+1]; rv.z = av[4*j+2]; rv.w = av[4*j+3];
    u4[j] = ru; v4[j] = rv;
  }
}

// flux[e] = relu(u[row[e],:] + v[col[e],:]) . We2 + be2    (8 threads/edge)
__global__ __launch_bounds__(256) void k_flux(
    const int* __restrict__ row, const int* __restrict__ col,
    const float* __restrict__ u, const float* __restrict__ v,
    const float* __restrict__ We2, const float* __restrict__ be2,
    float* __restrict__ out)
{
  int gid = blockIdx.x * 256 + threadIdx.x;
  int e = gid >> 3, q = gid & 7;
  if (e >= NE) return;
  int r = row[e], c = col[e];
  float4 a = ((const float4*)u)[r * 8 + q];
  float4 b = ((const float4*)v)[c * 8 + q];
  float4 w = ((const float4*)We2)[q];
  float p = relu_(a.x + b.x) * w.x
          + relu_(a.y + b.y) * w.y
          + relu_(a.z + b.z) * w.z
          + relu_(a.w + b.w) * w.w;
  p += __shfl_xor(p, 1, 8);
  p += __shfl_xor(p, 2, 8);
  p += __shfl_xor(p, 4, 8);
  if (q == 0) out[e] = p + be2[0];
}

extern "C" void kernel_launch(void* const* d_in, const int* in_sizes, int n_in,
                              void* d_out, int out_size, void* d_ws, size_t ws_size,
                              hipStream_t stream) {
  const float* nf   = (const float*)d_in[0];
  const int*   ei   = (const int*)d_in[1];   // [2, E] int32: row then col
  const float* Win  = (const float*)d_in[2];
  const float* bin  = (const float*)d_in[3];
  const float* Wupd = (const float*)d_in[4]; // [2, 64, 32]
  const float* bupd = (const float*)d_in[5]; // [2, 32]
  const float* We1  = (const float*)d_in[6]; // [64, 32]
  const float* be1  = (const float*)d_in[7];
  const float* We2  = (const float*)d_in[8]; // [32]
  const float* be2  = (const float*)d_in[9];
  float* out = (float*)d_out;

  const int* row = ei;
  const int* col = ei + NE;

  char* ws = (char*)d_ws;
  const size_t HB = (size_t)NN * 32 * 4;            // 12.8 MB
  float*        h      = (float*)(ws);
  float*        agg    = (float*)(ws + HB);         // u later; keys during sort
  unsigned int* keys   = (unsigned int*)(ws + HB);  // dead before agg written
  float*        v      = (float*)(ws + 2 * HB);
  int*          ecol   = (int*)(ws + 2 * HB);       // dead before v written
  int*          rowptr = (int*)(ws + 3 * HB);               // NN+1 ints
  int*          btot   = (int*)(ws + 3 * HB + 400512);      // NBUCK
  int*          bbase  = (int*)(ws + 3 * HB + 402560);      // NBUCK+1
  int*          cursorA= (int*)(ws + 3 * HB + 404608);      // NBUCK

  const int NB = (NN + 255) / 256;

  hipMemsetAsync(btot, 0, NBUCK * 4, stream);
  k_node_embed<<<NB, 256, 0, stream>>>(nf, Win, bin, h);
  k_histA<<<NBLK_A, 512, 0, stream>>>(row, btot);
  k_scanA<<<1, 512, 0, stream>>>(btot, bbase, cursorA);
  k_partition<<<NBLK_A, 512, 0, stream>>>(row, col, cursorA, keys);
  k_passB<<<NBUCK, 512, 0, stream>>>(bbase, keys, ecol, rowptr);

  for (int l = 0; l < 2; ++l) {
    k_aggregate<<<(NN * 8 + 255) / 256, 256, 0, stream>>>(rowptr, ecol, h, agg);
    k_update<<<NB, 256, 0, stream>>>(h, agg, Wupd + l * 2048, bupd + l * 32);
  }

  k_uv<<<NB, 256, 0, stream>>>(h, We1, be1, agg, v);
  k_flux<<<(NE * 8 + 255) / 256, 256, 0, stream>>>(row, col, agg, v, We2, be2, out);
}

// Round 4
// 300.920 us; speedup vs baseline: 7.6316x; 1.0581x over previous
//
#include <hip/hip_runtime.h>
#include <hip/hip_fp16.h>

#define NN 100000
#define NE 2500000
#define RANGE 256
#define NBUCK 391                       // ceil(NN/RANGE)
#define CHUNK 8192
#define NBLK_A ((NE + CHUNK - 1) / CHUNK)   // 306

__device__ __forceinline__ float relu_(float x){ return fmaxf(x, 0.f); }

// h[n, 0:32] = relu(nf[n,0:2] @ W_in + b_in)
__global__ __launch_bounds__(256) void k_node_embed(
    const float* __restrict__ nf, const float* __restrict__ Win,
    const float* __restrict__ bin, float* __restrict__ h)
{
  int n = blockIdx.x * 256 + threadIdx.x;
  if (n >= NN) return;
  float f0 = nf[2*n], f1 = nf[2*n+1];
  const float4* W0 = (const float4*)Win;
  const float4* W1 = (const float4*)(Win + 32);
  const float4* B  = (const float4*)bin;
  float4* h4 = (float4*)(h + (size_t)n * 32);
#pragma unroll
  for (int j = 0; j < 8; ++j) {
    float4 w0 = W0[j], w1 = W1[j], b = B[j], r;
    r.x = relu_(fmaf(f0, w0.x, fmaf(f1, w1.x, b.x)));
    r.y = relu_(fmaf(f0, w0.y, fmaf(f1, w1.y, b.y)));
    r.z = relu_(fmaf(f0, w0.z, fmaf(f1, w1.z, b.z)));
    r.w = relu_(fmaf(f0, w0.w, fmaf(f1, w1.w, b.w)));
    h4[j] = r;
  }
}

// ---- CSR build: counting sort, per-block histograms persisted ----

// pass A: per-block bucket histogram -> blockhist[bucket][block], totals -> btot
__global__ __launch_bounds__(512) void k_histA(const int* __restrict__ row,
                                               int* __restrict__ btot,
                                               int* __restrict__ blockhist)
{
  __shared__ int hist[NBUCK];
  int t = threadIdx.x;
  for (int i = t; i < NBUCK; i += 512) hist[i] = 0;
  __syncthreads();
  int e0 = blockIdx.x * CHUNK + t;
#pragma unroll
  for (int k = 0; k < CHUNK / 512; ++k) {
    int e = e0 + k * 512;
    if (e < NE) atomicAdd(&hist[row[e] >> 8], 1);
  }
  __syncthreads();
  for (int i = t; i < NBUCK; i += 512) {
    int c = hist[i];
    blockhist[(size_t)i * NBLK_A + blockIdx.x] = c;
    if (c) atomicAdd(&btot[i], c);
  }
}

// exclusive scan of bucket totals -> bbase
__global__ __launch_bounds__(512) void k_scanA(const int* __restrict__ btot,
                                               int* __restrict__ bbase)
{
  __shared__ int s[512];
  int t = threadIdx.x;
  int my = (t < NBUCK) ? btot[t] : 0;
  s[t] = my;
  __syncthreads();
  for (int off = 1; off < 512; off <<= 1) {
    int v = (t >= off) ? s[t - off] : 0;
    __syncthreads();
    s[t] += v;
    __syncthreads();
  }
  if (t < NBUCK) bbase[t] = s[t] - my;
  if (t == 0) bbase[NBUCK] = NE;
}

// per-bucket scan across blocks: blockhist[i][b] -> global base offset
__global__ __launch_bounds__(512) void k_colscan(int* __restrict__ blockhist,
                                                 const int* __restrict__ bbase)
{
  __shared__ int s[512];
  int i = blockIdx.x, t = threadIdx.x;
  int* rowp = blockhist + (size_t)i * NBLK_A;
  int my = (t < NBLK_A) ? rowp[t] : 0;
  s[t] = my;
  __syncthreads();
  for (int off = 1; off < 512; off <<= 1) {
    int v = (t >= off) ? s[t - off] : 0;
    __syncthreads();
    s[t] += v;
    __syncthreads();
  }
  if (t < NBLK_A) rowp[t] = bbase[i] + s[t] - my;   // exclusive + bucket base
}

// single-pass partition into bucket-contiguous packed keys: (col<<8)|(row&255)
__global__ __launch_bounds__(512) void k_partition(
    const int* __restrict__ row, const int* __restrict__ col,
    const int* __restrict__ blockhist, unsigned int* __restrict__ keys)
{
  __shared__ int cur[NBUCK];
  __shared__ int base[NBUCK];
  int t = threadIdx.x, b = blockIdx.x;
  for (int i = t; i < NBUCK; i += 512) {
    base[i] = blockhist[(size_t)i * NBLK_A + b];
    cur[i] = 0;
  }
  __syncthreads();
  int e0 = b * CHUNK + t;
#pragma unroll
  for (int k = 0; k < CHUNK / 512; ++k) {
    int e = e0 + k * 512;
    if (e < NE) {
      int r = row[e];
      int bi = r >> 8;
      int idx = atomicAdd(&cur[bi], 1);
      keys[base[bi] + idx] = ((unsigned)col[e] << 8) | (unsigned)(r & 255);
    }
  }
}

// per-bucket: 256-entry histogram + scan -> rowptr; place col into ecol
__global__ __launch_bounds__(512) void k_passB(
    const int* __restrict__ bbase, const unsigned int* __restrict__ keys,
    int* __restrict__ ecol, int* __restrict__ rowptr)
{
  __shared__ int hist[RANGE];
  __shared__ int sc[RANGE];
  int t = threadIdx.x, b = blockIdx.x;
  int s0 = bbase[b], e0 = bbase[b + 1];
  if (t < RANGE) hist[t] = 0;
  __syncthreads();
  for (int i = s0 + t; i < e0; i += 512)
    atomicAdd(&hist[keys[i] & 255u], 1);
  __syncthreads();
  int my = (t < RANGE) ? hist[t] : 0;
  if (t < RANGE) sc[t] = my;
  __syncthreads();
  for (int off = 1; off < RANGE; off <<= 1) {
    int v = 0;
    if (t < RANGE && t >= off) v = sc[t - off];
    __syncthreads();
    if (t < RANGE) sc[t] += v;
    __syncthreads();
  }
  if (t < RANGE) {
    int ex = sc[t] - my;
    int n = b * RANGE + t;
    if (n <= NN) rowptr[n] = s0 + ex;
    hist[t] = ex;                 // becomes the placement cursor
  }
  __syncthreads();
  for (int i = s0 + t; i < e0; i += 512) {
    unsigned key = keys[i];
    int rl = (int)(key & 255u);
    int idx = atomicAdd(&hist[rl], 1);
    ecol[s0 + idx] = (int)(key >> 8);
  }
}

// ---- aggregation as gather: agg[n,:] = mean_{i in seg(n)} h[ecol[i],:] ----
__global__ __launch_bounds__(256) void k_aggregate(
    const int* __restrict__ rowptr, const int* __restrict__ ecol,
    const float* __restrict__ h, float* __restrict__ agg)
{
  int gid = blockIdx.x * 256 + threadIdx.x;
  int n = gid >> 3, q = gid & 7;
  if (n >= NN) return;
  int s = rowptr[n], e = rowptr[n + 1];
  const float4* h4 = (const float4*)h;
  float4 acc = {0.f, 0.f, 0.f, 0.f};
  for (int i = s; i < e; ++i) {
    int c = ecol[i];
    float4 x = h4[c * 8 + q];
    acc.x += x.x; acc.y += x.y; acc.z += x.z; acc.w += x.w;
  }
  float dinv = 1.0f / fmaxf((float)(e - s), 1.0f);
  acc.x *= dinv; acc.y *= dinv; acc.z *= dinv; acc.w *= dinv;
  ((float4*)agg)[n * 8 + q] = acc;
}

// layer-1 update: h = relu(concat(h, agg) @ W + b)  (in place)
__global__ __launch_bounds__(256) void k_update(
    float* __restrict__ h, const float* __restrict__ agg,
    const float* __restrict__ W, const float* __restrict__ b)
{
  __shared__ float Ws[64 * 32];
  __shared__ float bs[32];
  int t = threadIdx.x;
  for (int i = t; i < 2048; i += 256) Ws[i] = W[i];
  if (t < 32) bs[t] = b[t];
  __syncthreads();
  int n = blockIdx.x * 256 + t;
  if (n >= NN) return;

  float x[64];
  const float4* h4 = (const float4*)(h + (size_t)n * 32);
  const float4* a4 = (const float4*)(agg + (size_t)n * 32);
#pragma unroll
  for (int j = 0; j < 8; ++j) {
    float4 tv = h4[j];
    x[4*j+0] = tv.x; x[4*j+1] = tv.y; x[4*j+2] = tv.z; x[4*j+3] = tv.w;
  }
#pragma unroll
  for (int j = 0; j < 8; ++j) {
    float4 tv = a4[j];
    x[32+4*j+0] = tv.x; x[32+4*j+1] = tv.y;
    x[32+4*j+2] = tv.z; x[32+4*j+3] = tv.w;
  }
  float acc[32];
#pragma unroll
  for (int j = 0; j < 32; ++j) acc[j] = bs[j];
#pragma unroll
  for (int k = 0; k < 64; ++k) {
    float xk = x[k];
    const float* wr = Ws + k * 32;
#pragma unroll
    for (int j = 0; j < 32; ++j) acc[j] = fmaf(xk, wr[j], acc[j]);
  }
  float4* o4 = (float4*)(h + (size_t)n * 32);
#pragma unroll
  for (int j = 0; j < 8; ++j) {
    float4 r;
    r.x = relu_(acc[4*j+0]); r.y = relu_(acc[4*j+1]);
    r.z = relu_(acc[4*j+2]); r.w = relu_(acc[4*j+3]);
    o4[j] = r;
  }
}

// layer-2 update fused with edge-MLP projection:
// h2 = relu(concat(h, agg) @ W + b)  (registers only)
// u = h2 @ We1[0:32,:] + be1 ; v = h2 @ We1[32:64,:]   (stored fp16)
__global__ __launch_bounds__(256) void k_update2_uv(
    const float* __restrict__ h, const float* __restrict__ agg,
    const float* __restrict__ W, const float* __restrict__ b,
    const float* __restrict__ We1, const float* __restrict__ be1,
    __half* __restrict__ u, __half* __restrict__ v)
{
  __shared__ float Ws[64 * 32];
  __shared__ float Es[64 * 32];
  __shared__ float bs[32];
  __shared__ float bes[32];
  int t = threadIdx.x;
  for (int i = t; i < 2048; i += 256) { Ws[i] = W[i]; Es[i] = We1[i]; }
  if (t < 32) { bs[t] = b[t]; bes[t] = be1[t]; }
  __syncthreads();
  int n = blockIdx.x * 256 + t;
  if (n >= NN) return;

  float x[64];
  const float4* h4 = (const float4*)(h + (size_t)n * 32);
  const float4* a4 = (const float4*)(agg + (size_t)n * 32);
#pragma unroll
  for (int j = 0; j < 8; ++j) {
    float4 tv = h4[j];
    x[4*j+0] = tv.x; x[4*j+1] = tv.y; x[4*j+2] = tv.z; x[4*j+3] = tv.w;
  }
#pragma unroll
  for (int j = 0; j < 8; ++j) {
    float4 tv = a4[j];
    x[32+4*j+0] = tv.x; x[32+4*j+1] = tv.y;
    x[32+4*j+2] = tv.z; x[32+4*j+3] = tv.w;
  }
  float h2[32];
#pragma unroll
  for (int j = 0; j < 32; ++j) h2[j] = bs[j];
#pragma unroll
  for (int k = 0; k < 64; ++k) {
    float xk = x[k];
    const float* wr = Ws + k * 32;
#pragma unroll
    for (int j = 0; j < 32; ++j) h2[j] = fmaf(xk, wr[j], h2[j]);
  }
#pragma unroll
  for (int j = 0; j < 32; ++j) h2[j] = relu_(h2[j]);

  float au[32], av[32];
#pragma unroll
  for (int j = 0; j < 32; ++j) { au[j] = bes[j]; av[j] = 0.f; }
#pragma unroll
  for (int k = 0; k < 32; ++k) {
    float hk = h2[k];
    const float* wu = Es + k * 32;
    const float* wv = Es + (32 + k) * 32;
#pragma unroll
    for (int j = 0; j < 32; ++j) {
      au[j] = fmaf(hk, wu[j], au[j]);
      av[j] = fmaf(hk, wv[j], av[j]);
    }
  }
  __half2* u2 = (__half2*)(u + (size_t)n * 32);
  __half2* v2 = (__half2*)(v + (size_t)n * 32);
#pragma unroll
  for (int j = 0; j < 16; ++j) {
    u2[j] = __floats2half2_rn(au[2*j], au[2*j+1]);
    v2[j] = __floats2half2_rn(av[2*j], av[2*j+1]);
  }
}

// flux[e] = relu(u[row[e],:] + v[col[e],:]) . We2 + be2    (8 threads/edge, fp16 u/v)
__global__ __launch_bounds__(256) void k_flux(
    const int* __restrict__ row, const int* __restrict__ col,
    const __half* __restrict__ u, const __half* __restrict__ v,
    const float* __restrict__ We2, const float* __restrict__ be2,
    float* __restrict__ out)
{
  int gid = blockIdx.x * 256 + threadIdx.x;
  int e = gid >> 3, q = gid & 7;
  if (e >= NE) return;
  int r = row[e], c = col[e];
  uint2 ua = ((const uint2*)u)[r * 8 + q];   // 4 halfs
  uint2 vb = ((const uint2*)v)[c * 8 + q];
  __half2 ua0 = *(const __half2*)&ua.x, ua1 = *(const __half2*)&ua.y;
  __half2 vb0 = *(const __half2*)&vb.x, vb1 = *(const __half2*)&vb.y;
  float2 a0 = __half22float2(ua0), a1 = __half22float2(ua1);
  float2 b0 = __half22float2(vb0), b1 = __half22float2(vb1);
  float4 w = ((const float4*)We2)[q];
  float p = relu_(a0.x + b0.x) * w.x
          + relu_(a0.y + b0.y) * w.y
          + relu_(a1.x + b1.x) * w.z
          + relu_(a1.y + b1.y) * w.w;
  p += __shfl_xor(p, 1, 8);
  p += __shfl_xor(p, 2, 8);
  p += __shfl_xor(p, 4, 8);
  if (q == 0) out[e] = p + be2[0];
}

extern "C" void kernel_launch(void* const* d_in, const int* in_sizes, int n_in,
                              void* d_out, int out_size, void* d_ws, size_t ws_size,
                              hipStream_t stream) {
  const float* nf   = (const float*)d_in[0];
  const int*   ei   = (const int*)d_in[1];   // [2, E] int32: row then col
  const float* Win  = (const float*)d_in[2];
  const float* bin  = (const float*)d_in[3];
  const float* Wupd = (const float*)d_in[4]; // [2, 64, 32]
  const float* bupd = (const float*)d_in[5]; // [2, 32]
  const float* We1  = (const float*)d_in[6]; // [64, 32]
  const float* be1  = (const float*)d_in[7];
  const float* We2  = (const float*)d_in[8]; // [32]
  const float* be2  = (const float*)d_in[9];
  float* out = (float*)d_out;

  const int* row = ei;
  const int* col = ei + NE;

  char* ws = (char*)d_ws;
  const size_t HB = (size_t)NN * 32 * 4;            // 12.8 MB
  float*        h      = (float*)(ws);
  float*        agg    = (float*)(ws + HB);         // keys alias (dead before agg)
  unsigned int* keys   = (unsigned int*)(ws + HB);
  int*          ecol   = (int*)(ws + 2 * HB);       // dead before u,v written
  __half*       u      = (__half*)(ws + 2 * HB);            // 6.4 MB
  __half*       v      = (__half*)(ws + 2 * HB + HB / 2);   // 6.4 MB
  int*          rowptr = (int*)(ws + 3 * HB);               // NN+1 ints
  int*          btot   = (int*)(ws + 3 * HB + 400512);      // NBUCK
  int*          bbase  = (int*)(ws + 3 * HB + 402560);      // NBUCK+1
  int*          blockhist = (int*)(ws + 3 * HB + 404608);   // NBUCK*NBLK_A ints

  const int NB = (NN + 255) / 256;

  hipMemsetAsync(btot, 0, NBUCK * 4, stream);
  k_node_embed<<<NB, 256, 0, stream>>>(nf, Win, bin, h);
  k_histA<<<NBLK_A, 512, 0, stream>>>(row, btot, blockhist);
  k_scanA<<<1, 512, 0, stream>>>(btot, bbase);
  k_colscan<<<NBUCK, 512, 0, stream>>>(blockhist, bbase);
  k_partition<<<NBLK_A, 512, 0, stream>>>(row, col, blockhist, keys);
  k_passB<<<NBUCK, 512, 0, stream>>>(bbase, keys, ecol, rowptr);

  k_aggregate<<<(NN * 8 + 255) / 256, 256, 0, stream>>>(rowptr, ecol, h, agg);
  k_update<<<NB, 256, 0, stream>>>(h, agg, Wupd, bupd);

  k_aggregate<<<(NN * 8 + 255) / 256, 256, 0, stream>>>(rowptr, ecol, h, agg);
  k_update2_uv<<<NB, 256, 0, stream>>>(h, agg, Wupd + 2048, bupd + 32,
                                       We1, be1, u, v);

  k_flux<<<(NE * 8 + 255) / 256, 256, 0, stream>>>(row, col, u, v, We2, be2, out);
}

// Round 5
// 276.487 us; speedup vs baseline: 8.3060x; 1.0884x over previous
//
#include <hip/hip_runtime.h>
#include <hip/hip_fp16.h>

#define NN 100000
#define NE 2500000
#define RANGE 256
#define NBUCK 391                       // ceil(NN/RANGE)
#define CHUNK 8192
#define NBLK_A ((NE + CHUNK - 1) / CHUNK)   // 306

__device__ __forceinline__ float relu_(float x){ return fmaxf(x, 0.f); }

// h[n,0:32] = relu(nf[n,0:2] @ W_in + b_in); also fp16 mirror h16
__global__ __launch_bounds__(256) void k_node_embed(
    const float* __restrict__ nf, const float* __restrict__ Win,
    const float* __restrict__ bin, float* __restrict__ h,
    __half* __restrict__ h16)
{
  int n = blockIdx.x * 256 + threadIdx.x;
  if (n >= NN) return;
  float f0 = nf[2*n], f1 = nf[2*n+1];
  const float4* W0 = (const float4*)Win;
  const float4* W1 = (const float4*)(Win + 32);
  const float4* B  = (const float4*)bin;
  float4* h4 = (float4*)(h + (size_t)n * 32);
  __half2* g2 = (__half2*)(h16 + (size_t)n * 32);
#pragma unroll
  for (int j = 0; j < 8; ++j) {
    float4 w0 = W0[j], w1 = W1[j], b = B[j], r;
    r.x = relu_(fmaf(f0, w0.x, fmaf(f1, w1.x, b.x)));
    r.y = relu_(fmaf(f0, w0.y, fmaf(f1, w1.y, b.y)));
    r.z = relu_(fmaf(f0, w0.z, fmaf(f1, w1.z, b.z)));
    r.w = relu_(fmaf(f0, w0.w, fmaf(f1, w1.w, b.w)));
    h4[j] = r;
    g2[2*j]   = __floats2half2_rn(r.x, r.y);
    g2[2*j+1] = __floats2half2_rn(r.z, r.w);
  }
}

// ---- CSR build: counting sort, per-block histograms persisted ----

__global__ __launch_bounds__(512) void k_histA(const int* __restrict__ row,
                                               int* __restrict__ btot,
                                               int* __restrict__ blockhist)
{
  __shared__ int hist[NBUCK];
  int t = threadIdx.x;
  for (int i = t; i < NBUCK; i += 512) hist[i] = 0;
  __syncthreads();
  int e0 = blockIdx.x * CHUNK + t;
#pragma unroll
  for (int k = 0; k < CHUNK / 512; ++k) {
    int e = e0 + k * 512;
    if (e < NE) atomicAdd(&hist[row[e] >> 8], 1);
  }
  __syncthreads();
  for (int i = t; i < NBUCK; i += 512) {
    int c = hist[i];
    blockhist[(size_t)i * NBLK_A + blockIdx.x] = c;
    if (c) atomicAdd(&btot[i], c);
  }
}

__global__ __launch_bounds__(512) void k_scanA(const int* __restrict__ btot,
                                               int* __restrict__ bbase)
{
  __shared__ int s[512];
  int t = threadIdx.x;
  int my = (t < NBUCK) ? btot[t] : 0;
  s[t] = my;
  __syncthreads();
  for (int off = 1; off < 512; off <<= 1) {
    int v = (t >= off) ? s[t - off] : 0;
    __syncthreads();
    s[t] += v;
    __syncthreads();
  }
  if (t < NBUCK) bbase[t] = s[t] - my;
  if (t == 0) bbase[NBUCK] = NE;
}

__global__ __launch_bounds__(512) void k_colscan(int* __restrict__ blockhist,
                                                 const int* __restrict__ bbase)
{
  __shared__ int s[512];
  int i = blockIdx.x, t = threadIdx.x;
  int* rowp = blockhist + (size_t)i * NBLK_A;
  int my = (t < NBLK_A) ? rowp[t] : 0;
  s[t] = my;
  __syncthreads();
  for (int off = 1; off < 512; off <<= 1) {
    int v = (t >= off) ? s[t - off] : 0;
    __syncthreads();
    s[t] += v;
    __syncthreads();
  }
  if (t < NBLK_A) rowp[t] = bbase[i] + s[t] - my;
}

__global__ __launch_bounds__(512) void k_partition(
    const int* __restrict__ row, const int* __restrict__ col,
    const int* __restrict__ blockhist, unsigned int* __restrict__ keys)
{
  __shared__ int cur[NBUCK];
  __shared__ int base[NBUCK];
  int t = threadIdx.x, b = blockIdx.x;
  for (int i = t; i < NBUCK; i += 512) {
    base[i] = blockhist[(size_t)i * NBLK_A + b];
    cur[i] = 0;
  }
  __syncthreads();
  int e0 = b * CHUNK + t;
#pragma unroll
  for (int k = 0; k < CHUNK / 512; ++k) {
    int e = e0 + k * 512;
    if (e < NE) {
      int r = row[e];
      int bi = r >> 8;
      int idx = atomicAdd(&cur[bi], 1);
      keys[base[bi] + idx] = ((unsigned)col[e] << 8) | (unsigned)(r & 255);
    }
  }
}

__global__ __launch_bounds__(512) void k_passB(
    const int* __restrict__ bbase, const unsigned int* __restrict__ keys,
    int* __restrict__ ecol, int* __restrict__ rowptr)
{
  __shared__ int hist[RANGE];
  __shared__ int sc[RANGE];
  int t = threadIdx.x, b = blockIdx.x;
  int s0 = bbase[b], e0 = bbase[b + 1];
  if (t < RANGE) hist[t] = 0;
  __syncthreads();
  for (int i = s0 + t; i < e0; i += 512)
    atomicAdd(&hist[keys[i] & 255u], 1);
  __syncthreads();
  int my = (t < RANGE) ? hist[t] : 0;
  if (t < RANGE) sc[t] = my;
  __syncthreads();
  for (int off = 1; off < RANGE; off <<= 1) {
    int v = 0;
    if (t < RANGE && t >= off) v = sc[t - off];
    __syncthreads();
    if (t < RANGE) sc[t] += v;
    __syncthreads();
  }
  if (t < RANGE) {
    int ex = sc[t] - my;
    int n = b * RANGE + t;
    if (n <= NN) rowptr[n] = s0 + ex;
    hist[t] = ex;
  }
  __syncthreads();
  for (int i = s0 + t; i < e0; i += 512) {
    unsigned key = keys[i];
    int rl = (int)(key & 255u);
    int idx = atomicAdd(&hist[rl], 1);
    ecol[s0 + idx] = (int)(key >> 8);
  }
}

// ---- aggregation: agg[n,:] = mean h16[ecol[i],:]  (4 lanes/node, uint4 loads) ----
__global__ __launch_bounds__(256) void k_aggregate(
    const int* __restrict__ rowptr, const int* __restrict__ ecol,
    const __half* __restrict__ h16, float* __restrict__ agg)
{
  int gid = blockIdx.x * 256 + threadIdx.x;
  int n = gid >> 2, q = gid & 3;
  if (n >= NN) return;
  int s = rowptr[n], e = rowptr[n + 1];
  const uint4* hv = (const uint4*)h16;   // 8 halfs per uint4; 4 per node
  float acc[8];
#pragma unroll
  for (int j = 0; j < 8; ++j) acc[j] = 0.f;
  for (int i = s; i < e; ++i) {
    int c = ecol[i];
    uint4 x = hv[c * 4 + q];
    const __half2* hp = (const __half2*)&x;
#pragma unroll
    for (int k = 0; k < 4; ++k) {
      float2 f = __half22float2(hp[k]);
      acc[2*k]   += f.x;
      acc[2*k+1] += f.y;
    }
  }
  float dinv = 1.0f / fmaxf((float)(e - s), 1.0f);
  float4* o = (float4*)(agg + (size_t)n * 32 + q * 8);
  float4 r0, r1;
  r0.x = acc[0]*dinv; r0.y = acc[1]*dinv; r0.z = acc[2]*dinv; r0.w = acc[3]*dinv;
  r1.x = acc[4]*dinv; r1.y = acc[5]*dinv; r1.z = acc[6]*dinv; r1.w = acc[7]*dinv;
  o[0] = r0; o[1] = r1;
}

// layer-1 update: h = relu(concat(h, agg) @ W + b); refresh h16
__global__ __launch_bounds__(256) void k_update(
    float* __restrict__ h, const float* __restrict__ agg,
    const float* __restrict__ W, const float* __restrict__ b,
    __half* __restrict__ h16)
{
  __shared__ float Ws[64 * 32];
  __shared__ float bs[32];
  int t = threadIdx.x;
  for (int i = t; i < 2048; i += 256) Ws[i] = W[i];
  if (t < 32) bs[t] = b[t];
  __syncthreads();
  int n = blockIdx.x * 256 + t;
  if (n >= NN) return;

  float x[64];
  const float4* h4 = (const float4*)(h + (size_t)n * 32);
  const float4* a4 = (const float4*)(agg + (size_t)n * 32);
#pragma unroll
  for (int j = 0; j < 8; ++j) {
    float4 tv = h4[j];
    x[4*j+0] = tv.x; x[4*j+1] = tv.y; x[4*j+2] = tv.z; x[4*j+3] = tv.w;
  }
#pragma unroll
  for (int j = 0; j < 8; ++j) {
    float4 tv = a4[j];
    x[32+4*j+0] = tv.x; x[32+4*j+1] = tv.y;
    x[32+4*j+2] = tv.z; x[32+4*j+3] = tv.w;
  }
  float acc[32];
#pragma unroll
  for (int j = 0; j < 32; ++j) acc[j] = bs[j];
#pragma unroll
  for (int k = 0; k < 64; ++k) {
    float xk = x[k];
    const float* wr = Ws + k * 32;
#pragma unroll
    for (int j = 0; j < 32; ++j) acc[j] = fmaf(xk, wr[j], acc[j]);
  }
  float4* o4 = (float4*)(h + (size_t)n * 32);
  __half2* g2 = (__half2*)(h16 + (size_t)n * 32);
#pragma unroll
  for (int j = 0; j < 8; ++j) {
    float4 r;
    r.x = relu_(acc[4*j+0]); r.y = relu_(acc[4*j+1]);
    r.z = relu_(acc[4*j+2]); r.w = relu_(acc[4*j+3]);
    o4[j] = r;
    g2[2*j]   = __floats2half2_rn(r.x, r.y);
    g2[2*j+1] = __floats2half2_rn(r.z, r.w);
  }
}

// layer-2 update fused with edge-MLP projection (u,v fp16 out)
__global__ __launch_bounds__(256) void k_update2_uv(
    const float* __restrict__ h, const float* __restrict__ agg,
    const float* __restrict__ W, const float* __restrict__ b,
    const float* __restrict__ We1, const float* __restrict__ be1,
    __half* __restrict__ u, __half* __restrict__ v)
{
  __shared__ float Ws[64 * 32];
  __shared__ float Es[64 * 32];
  __shared__ float bs[32];
  __shared__ float bes[32];
  int t = threadIdx.x;
  for (int i = t; i < 2048; i += 256) { Ws[i] = W[i]; Es[i] = We1[i]; }
  if (t < 32) { bs[t] = b[t]; bes[t] = be1[t]; }
  __syncthreads();
  int n = blockIdx.x * 256 + t;
  if (n >= NN) return;

  float x[64];
  const float4* h4 = (const float4*)(h + (size_t)n * 32);
  const float4* a4 = (const float4*)(agg + (size_t)n * 32);
#pragma unroll
  for (int j = 0; j < 8; ++j) {
    float4 tv = h4[j];
    x[4*j+0] = tv.x; x[4*j+1] = tv.y; x[4*j+2] = tv.z; x[4*j+3] = tv.w;
  }
#pragma unroll
  for (int j = 0; j < 8; ++j) {
    float4 tv = a4[j];
    x[32+4*j+0] = tv.x; x[32+4*j+1] = tv.y;
    x[32+4*j+2] = tv.z; x[32+4*j+3] = tv.w;
  }
  float h2[32];
#pragma unroll
  for (int j = 0; j < 32; ++j) h2[j] = bs[j];
#pragma unroll
  for (int k = 0; k < 64; ++k) {
    float xk = x[k];
    const float* wr = Ws + k * 32;
#pragma unroll
    for (int j = 0; j < 32; ++j) h2[j] = fmaf(xk, wr[j], h2[j]);
  }
#pragma unroll
  for (int j = 0; j < 32; ++j) h2[j] = relu_(h2[j]);

  float au[32], av[32];
#pragma unroll
  for (int j = 0; j < 32; ++j) { au[j] = bes[j]; av[j] = 0.f; }
#pragma unroll
  for (int k = 0; k < 32; ++k) {
    float hk = h2[k];
    const float* wu = Es + k * 32;
    const float* wv = Es + (32 + k) * 32;
#pragma unroll
    for (int j = 0; j < 32; ++j) {
      au[j] = fmaf(hk, wu[j], au[j]);
      av[j] = fmaf(hk, wv[j], av[j]);
    }
  }
  __half2* u2 = (__half2*)(u + (size_t)n * 32);
  __half2* v2 = (__half2*)(v + (size_t)n * 32);
#pragma unroll
  for (int j = 0; j < 16; ++j) {
    u2[j] = __floats2half2_rn(au[2*j], au[2*j+1]);
    v2[j] = __floats2half2_rn(av[2*j], av[2*j+1]);
  }
}

// flux[e] = relu(u[row]+v[col]).We2 + be2   (4 lanes/edge, uint4 fp16 loads)
__global__ __launch_bounds__(256) void k_flux(
    const int* __restrict__ row, const int* __restrict__ col,
    const __half* __restrict__ u, const __half* __restrict__ v,
    const float* __restrict__ We2, const float* __restrict__ be2,
    float* __restrict__ out)
{
  int gid = blockIdx.x * 256 + threadIdx.x;
  int e = gid >> 2, q = gid & 3;
  if (e >= NE) return;
  int r = row[e], c = col[e];
  uint4 ua = ((const uint4*)u)[r * 4 + q];   // 8 halfs
  uint4 vb = ((const uint4*)v)[c * 4 + q];
  const __half2* ah = (const __half2*)&ua;
  const __half2* bh = (const __half2*)&vb;
  const float4* w4 = (const float4*)(We2 + q * 8);
  float4 w0 = w4[0], w1 = w4[1];
  float p = 0.f;
  {
    float2 a = __half22float2(ah[0]), b = __half22float2(bh[0]);
    p += relu_(a.x + b.x) * w0.x + relu_(a.y + b.y) * w0.y;
    a = __half22float2(ah[1]); b = __half22float2(bh[1]);
    p += relu_(a.x + b.x) * w0.z + relu_(a.y + b.y) * w0.w;
    a = __half22float2(ah[2]); b = __half22float2(bh[2]);
    p += relu_(a.x + b.x) * w1.x + relu_(a.y + b.y) * w1.y;
    a = __half22float2(ah[3]); b = __half22float2(bh[3]);
    p += relu_(a.x + b.x) * w1.z + relu_(a.y + b.y) * w1.w;
  }
  p += __shfl_xor(p, 1, 4);
  p += __shfl_xor(p, 2, 4);
  if (q == 0) out[e] = p + be2[0];
}

extern "C" void kernel_launch(void* const* d_in, const int* in_sizes, int n_in,
                              void* d_out, int out_size, void* d_ws, size_t ws_size,
                              hipStream_t stream) {
  const float* nf   = (const float*)d_in[0];
  const int*   ei   = (const int*)d_in[1];
  const float* Win  = (const float*)d_in[2];
  const float* bin  = (const float*)d_in[3];
  const float* Wupd = (const float*)d_in[4];
  const float* bupd = (const float*)d_in[5];
  const float* We1  = (const float*)d_in[6];
  const float* be1  = (const float*)d_in[7];
  const float* We2  = (const float*)d_in[8];
  const float* be2  = (const float*)d_in[9];
  float* out = (float*)d_out;

  const int* row = ei;
  const int* col = ei + NE;

  char* ws = (char*)d_ws;
  const size_t HB  = (size_t)NN * 32 * 4;   // 12.8 MB
  const size_t HB2 = HB / 2;                // 6.4 MB
  float*        h      = (float*)(ws);                       // 12.8
  __half*       h16    = (__half*)(ws + HB);                 // 6.4
  float*        agg    = (float*)(ws + HB + HB2);            // 12.8 (keys alias)
  unsigned int* keys   = (unsigned int*)(ws + HB + HB2);     // dead before agg
  int*          ecol   = (int*)(ws + 2 * HB + HB2);          // 10 MB (u,v alias)
  __half*       u      = (__half*)(ws + 2 * HB + HB2);       // 6.4 (after ecol dead)
  __half*       v      = (__half*)(ws + 2 * HB + 2 * HB2);   // 6.4
  char*         tail   = ws + 3 * HB + HB2;                  // 12.8+6.4+12.8+12.8
  int*          rowptr = (int*)(tail);                       // NN+1 ints
  int*          btot   = (int*)(tail + 400512);
  int*          bbase  = (int*)(tail + 402560);
  int*          blockhist = (int*)(tail + 404608);           // NBUCK*NBLK_A

  const int NB = (NN + 255) / 256;

  hipMemsetAsync(btot, 0, NBUCK * 4, stream);
  k_node_embed<<<NB, 256, 0, stream>>>(nf, Win, bin, h, h16);
  k_histA<<<NBLK_A, 512, 0, stream>>>(row, btot, blockhist);
  k_scanA<<<1, 512, 0, stream>>>(btot, bbase);
  k_colscan<<<NBUCK, 512, 0, stream>>>(blockhist, bbase);
  k_partition<<<NBLK_A, 512, 0, stream>>>(row, col, blockhist, keys);
  k_passB<<<NBUCK, 512, 0, stream>>>(bbase, keys, ecol, rowptr);

  k_aggregate<<<(NN * 4 + 255) / 256, 256, 0, stream>>>(rowptr, ecol, h16, agg);
  k_update<<<NB, 256, 0, stream>>>(h, agg, Wupd, bupd, h16);

  k_aggregate<<<(NN * 4 + 255) / 256, 256, 0, stream>>>(rowptr, ecol, h16, agg);
  k_update2_uv<<<NB, 256, 0, stream>>>(h, agg, Wupd + 2048, bupd + 32,
                                       We1, be1, u, v);

  k_flux<<<(NE * 4 + 255) / 256, 256, 0, stream>>>(row, col, u, v, We2, be2, out);
}